// Round 1
// baseline (209.313 us; speedup 1.0000x reference)
//
#include <hip/hip_runtime.h>

// ---------------------------------------------------------------------------
// FISTA sparse coding, restructured:
//   L = ||A||_F^2 ; M = A A^T / L (128x128, symmetric, bf16)
//   B = X A^T / L (computed per-block in fista prologue via MFMA)
//   iterate 80x:  zpre = z + B - z@M ; x = soft(zpre, 0.2/L) ;
//                 z = x + ((t-1)/t_new)(x - x_old)
// ---------------------------------------------------------------------------

typedef __attribute__((ext_vector_type(8))) __bf16 bf16x8;
typedef __attribute__((ext_vector_type(4))) float f32x4;
typedef __attribute__((ext_vector_type(8))) unsigned short u16x8;
typedef __attribute__((ext_vector_type(4))) unsigned short u16x4;

#define NITER 80

__device__ __forceinline__ unsigned short f2bf(float f) {
  unsigned int u = __builtin_bit_cast(unsigned int, f);
  u += 0x7FFFu + ((u >> 16) & 1u);   // RNE
  return (unsigned short)(u >> 16);
}

// ---- kernel 1: A(f32) -> A_bf16, plus per-block partial sums of A^2 --------
__global__ __launch_bounds__(256) void prep_a(const float* __restrict__ A,
                                              unsigned short* __restrict__ Abf,
                                              float* __restrict__ partials) {
  int tid = threadIdx.x;
  int idx = (blockIdx.x * 256 + tid) * 4;          // 128 blocks * 1024 f32
  float4 v = *(const float4*)(A + idx);
  u16x4 o;
  o[0] = f2bf(v.x); o[1] = f2bf(v.y); o[2] = f2bf(v.z); o[3] = f2bf(v.w);
  *(u16x4*)(Abf + idx) = o;
  float p = v.x * v.x + v.y * v.y + v.z * v.z + v.w * v.w;
#pragma unroll
  for (int m = 32; m >= 1; m >>= 1) p += __shfl_xor(p, m, 64);
  __shared__ float red[4];
  if ((tid & 63) == 0) red[tid >> 6] = p;
  __syncthreads();
  if (tid == 0) partials[blockIdx.x] = red[0] + red[1] + red[2] + red[3];
}

// ---- kernel 2: M_bf16[k][j] = bf16(dot(A_k, A_j)/L); also store L ----------
__global__ __launch_bounds__(256) void prep_m(const float* __restrict__ A,
                                              const float* __restrict__ partials,
                                              float* __restrict__ Lout,
                                              unsigned short* __restrict__ Mb) {
  int tid = threadIdx.x;
  int k = blockIdx.x;
  int w = tid >> 6, l = tid & 63;
  __shared__ float ak[1024];
  *(float4*)(ak + tid * 4) = *(const float4*)(A + k * 1024 + tid * 4);
  float L = 0.f;
#pragma unroll 1
  for (int i = 0; i < 128; ++i) L += partials[i];  // fixed order: deterministic
  float invL = 1.0f / L;
  if (k == 0 && tid == 0) Lout[0] = L;
  __syncthreads();
#pragma unroll 1
  for (int jj = 0; jj < 32; ++jj) {
    int j = w * 32 + jj;
    const float* aj = A + j * 1024;
    float p = 0.f;
#pragma unroll
    for (int q = 0; q < 4; ++q) {
      float4 x = *(const float4*)(aj + q * 256 + l * 4);
      float4 y = *(const float4*)(ak + q * 256 + l * 4);
      p += x.x * y.x + x.y * y.y + x.z * y.z + x.w * y.w;
    }
#pragma unroll
    for (int m = 32; m >= 1; m >>= 1) p += __shfl_xor(p, m, 64);
    if (l == 0) Mb[k * 128 + j] = f2bf(p * invL);
  }
}

// ---- kernel 3: persistent FISTA, 64 samples per block ----------------------
// wave w: sh = w>>1 owns sample rows [32sh,32sh+32); jh = w&1 owns codes
// [64jh, 64jh+64). Per lane (li=l&15, b=l>>4) state in C/D layout:
//   sample s = 32sh+16st+4b+r , code j = 64jh+16jt+li   (st<2, jt<4, r<4)
__global__ __launch_bounds__(256, 2) void fista(const float* __restrict__ X,
                                                const unsigned short* __restrict__ Abf,
                                                const unsigned short* __restrict__ Mb,
                                                const float* __restrict__ Lptr,
                                                float* __restrict__ out) {
  int tid = threadIdx.x;
  int w = tid >> 6, l = tid & 63;
  int li = l & 15, b = l >> 4;
  int sh = w >> 1, jh = w & 1;
  int s0 = blockIdx.x * 64;

  // z as bf16, [64 rows][16 chunks of 8 bf16], chunk index XOR-swizzled by row&15
  __shared__ __align__(16) unsigned short zls[64 * 128];

  float L = Lptr[0];
  float invL = 1.0f / L;
  float thr = 0.2f / L;

  // M fragments, held in registers for the whole kernel (symmetric M => both
  // operands read contiguous-k rows).  B-frag(jt,ks): M[16jt+64jh+li][32ks+8b..+8]
  bf16x8 mfr[4][4];
#pragma unroll
  for (int jt = 0; jt < 4; ++jt)
#pragma unroll
    for (int ks = 0; ks < 4; ++ks)
      mfr[jt][ks] = *(const bf16x8*)(Mb + (64 * jh + 16 * jt + li) * 128 + 32 * ks + 8 * b);

  // ---- prologue: acc = X_tile @ Abf^T  (K=1024), then Bn = -acc*invL ----
  f32x4 acc[2][4];
#pragma unroll
  for (int st = 0; st < 2; ++st)
#pragma unroll
    for (int jt = 0; jt < 4; ++jt)
      acc[st][jt] = f32x4{0.f, 0.f, 0.f, 0.f};

  int srow = tid >> 2, sc = tid & 3;          // X-stage: one 16B chunk/thread
  unsigned short* xstage = zls;               // [64][4 chunks], swizzle ^ (row&3)
#pragma unroll 1
  for (int ks = 0; ks < 32; ++ks) {
    const float* xp = X + (size_t)(s0 + srow) * 1024 + ks * 32 + sc * 8;
    float4 v0 = *(const float4*)(xp);
    float4 v1 = *(const float4*)(xp + 4);
    u16x8 st8;
    st8[0] = f2bf(v0.x); st8[1] = f2bf(v0.y); st8[2] = f2bf(v0.z); st8[3] = f2bf(v0.w);
    st8[4] = f2bf(v1.x); st8[5] = f2bf(v1.y); st8[6] = f2bf(v1.z); st8[7] = f2bf(v1.w);
    __syncthreads();                          // WAR: previous chunk consumed
    *(u16x8*)(xstage + srow * 32 + ((sc ^ (srow & 3)) * 8)) = st8;
    bf16x8 af[4];
#pragma unroll
    for (int jt = 0; jt < 4; ++jt)
      af[jt] = *(const bf16x8*)(Abf + (size_t)(64 * jh + 16 * jt + li) * 1024 + ks * 32 + 8 * b);
    __syncthreads();                          // RAW: stage visible
#pragma unroll
    for (int st = 0; st < 2; ++st) {
      int row = 32 * sh + 16 * st + li;
      bf16x8 xf = *(const bf16x8*)(xstage + row * 32 + ((b ^ (row & 3)) * 8));
#pragma unroll
      for (int jt = 0; jt < 4; ++jt)
        acc[st][jt] = __builtin_amdgcn_mfma_f32_16x16x32_bf16(xf, af[jt], acc[st][jt], 0, 0, 0);
    }
  }

  f32x4 Bn[2][4], xr[2][4], zr[2][4];
#pragma unroll
  for (int st = 0; st < 2; ++st)
#pragma unroll
    for (int jt = 0; jt < 4; ++jt) {
      Bn[st][jt] = -(acc[st][jt] * invL);     // Bn = -B  (so C-init = Bn - z)
      xr[st][jt] = f32x4{0.f, 0.f, 0.f, 0.f};
      zr[st][jt] = f32x4{0.f, 0.f, 0.f, 0.f};
    }

  __syncthreads();
#pragma unroll
  for (int i = 0; i < 4; ++i)                 // zero z_lds (z0 = 0)
    *(u16x8*)(zls + (tid + i * 256) * 8) = u16x8{0, 0, 0, 0, 0, 0, 0, 0};
  __syncthreads();

  float t = 1.0f;
#pragma unroll 1
  for (int it = 0; it < NITER; ++it) {
    float tn = 0.5f * (1.0f + sqrtf(1.0f + 4.0f * t * t));
    float c = (t - 1.0f) / tn;
    t = tn;
    float cp = 1.0f + c;

    f32x4 D[2][4];
#pragma unroll
    for (int st = 0; st < 2; ++st) {
      int row = 32 * sh + 16 * st + li;       // row & 15 == li
      bf16x8 zf[4];
#pragma unroll
      for (int ks = 0; ks < 4; ++ks)
        zf[ks] = *(const bf16x8*)(zls + row * 128 + (((4 * ks + b) ^ li) * 8));
#pragma unroll
      for (int jt = 0; jt < 4; ++jt) {
        f32x4 d = Bn[st][jt] - zr[st][jt];    // C = -B - z
        d = __builtin_amdgcn_mfma_f32_16x16x32_bf16(zf[0], mfr[jt][0], d, 0, 0, 0);
        d = __builtin_amdgcn_mfma_f32_16x16x32_bf16(zf[1], mfr[jt][1], d, 0, 0, 0);
        d = __builtin_amdgcn_mfma_f32_16x16x32_bf16(zf[2], mfr[jt][2], d, 0, 0, 0);
        d = __builtin_amdgcn_mfma_f32_16x16x32_bf16(zf[3], mfr[jt][3], d, 0, 0, 0);
        D[st][jt] = d;                        // D = z@M - z - B  => zpre = -D
      }
    }
    __syncthreads();                          // WAR: all reads of zls done
#pragma unroll
    for (int st = 0; st < 2; ++st)
#pragma unroll
      for (int jt = 0; jt < 4; ++jt) {
        f32x4 dd = D[st][jt];
        f32x4 xo = xr[st][jt];
        f32x4 xn, zm;
#pragma unroll
        for (int r = 0; r < 4; ++r) {
          float d1 = dd[r];
          float cl = fminf(fmaxf(d1, -thr), thr);
          float x1 = cl - d1;                 // soft(-d1, thr)
          xn[r] = x1;
          zm[r] = cp * x1 - c * xo[r];        // momentum
        }
        xr[st][jt] = xn;
        zr[st][jt] = zm;
        int cw = 8 * jh + 2 * jt + (li >> 3); // logical 8-elem chunk of code dim
        int colb = li & 7;
#pragma unroll
        for (int r = 0; r < 4; ++r) {
          int row = 32 * sh + 16 * st + 4 * b + r;   // row & 15 == 4b + r
          zls[row * 128 + ((cw ^ (4 * b + r)) * 8) + colb] = f2bf(zm[r]);
        }
      }
    __syncthreads();                          // RAW: z visible for next iter
  }

#pragma unroll
  for (int st = 0; st < 2; ++st)
#pragma unroll
    for (int jt = 0; jt < 4; ++jt)
#pragma unroll
      for (int r = 0; r < 4; ++r) {
        int s = s0 + 32 * sh + 16 * st + 4 * b + r;
        out[(size_t)s * 128 + 64 * jh + 16 * jt + li] = xr[st][jt][r];
      }
}

extern "C" void kernel_launch(void* const* d_in, const int* in_sizes, int n_in,
                              void* d_out, int out_size, void* d_ws, size_t ws_size,
                              hipStream_t stream) {
  const float* X = (const float*)d_in[0];          // 32768 x 1024 f32
  const float* A = (const float*)d_in[1];          // 128 x 1024 f32
  float* out = (float*)d_out;                      // 32768 x 128 f32

  float* partials      = (float*)d_ws;                                   // 128 f32
  float* Lout          = (float*)((char*)d_ws + 512);                    // 1 f32
  unsigned short* Abf  = (unsigned short*)((char*)d_ws + 528);           // 256 KB
  unsigned short* Mb   = (unsigned short*)((char*)d_ws + 528 + 262144);  // 32 KB

  prep_a<<<128, 256, 0, stream>>>(A, Abf, partials);
  prep_m<<<128, 256, 0, stream>>>(A, partials, Lout, Mb);
  fista<<<512, 256, 0, stream>>>(X, Abf, Mb, Lout, out);
}